// Round 17
// baseline (176.813 us; speedup 1.0000x reference)
//
#include <hip/hip_runtime.h>
#include <math.h>

#define NBATCH 4
#define NSEQ   1024
#define RD     256
#define NHEAD  8
#define HD     64
#define NHD    512   // NHEAD*HD

typedef __attribute__((ext_vector_type(8)))  short  short8;
typedef __attribute__((ext_vector_type(4)))  short  short4v;
typedef __attribute__((ext_vector_type(4)))  float  float4v;
typedef __attribute__((ext_vector_type(16))) float  float16v;

#define MFMA16(a,b,c) __builtin_amdgcn_mfma_f32_16x16x32_bf16(a,b,c,0,0,0)
#define MFMA32(a,b,c) __builtin_amdgcn_mfma_f32_32x32x16_bf16(a,b,c,0,0,0)

typedef const void __attribute__((address_space(1)))* gas_t;
typedef void __attribute__((address_space(3)))* las_t;
#define GLOAD16(g, l) __builtin_amdgcn_global_load_lds((gas_t)(g), (las_t)(l), 16, 0, 0)

static __device__ __forceinline__ unsigned short f2b(float f) {
    union { float f; unsigned u; } x; x.f = f;
    unsigned r = x.u + 0x7fffu + ((x.u >> 16) & 1u);   // RNE; inputs finite
    return (unsigned short)(r >> 16);
}
static __device__ __forceinline__ void st4(short* dst, float4v v) {
    short4v p;
    p[0] = (short)f2b(v[0]); p[1] = (short)f2b(v[1]);
    p[2] = (short)f2b(v[2]); p[3] = (short)f2b(v[3]);
    *(short4v*)dst = p;
}

// ---------------------------------------------------------------------------
// Bulk fp32 -> bf16 conversion of all inputs + mask normalization (y == 14).
// ---------------------------------------------------------------------------
struct ConvArgs { const float* src[15]; short* dst[15]; int n4[15]; };

__global__ __launch_bounds__(256) void convert_bf16(ConvArgs ca)
{
    const int a = blockIdx.y;
    if (a == 14) {                      // mask normalization (validated R4)
        if (blockIdx.x != 0) return;
        __shared__ int isByteLayout;
        const int t = threadIdx.x;      // 256 threads
        if (t == 0) isByteLayout = 0;
        __syncthreads();
        const int* mi = (const int*)ca.src[14];
        #pragma unroll
        for (int j = 0; j < 4; j++) {
            int v = mi[t*4 + j];        // first 4096 bytes under both layouts
            if (v & ~1) isByteLayout = 1;
        }
        __syncthreads();
        unsigned char* nm = (unsigned char*)ca.dst[14];
        const unsigned char* mb = (const unsigned char*)ca.src[14];
        if (isByteLayout) {
            #pragma unroll
            for (int j = 0; j < 16; j++) { int k = t*16 + j; nm[k] = mb[k] ? 1 : 0; }
        } else {
            #pragma unroll
            for (int j = 0; j < 16; j++) { int k = t*16 + j; nm[k] = mi[k] ? 1 : 0; }
        }
        return;
    }
    const float* __restrict__ s = ca.src[a];
    short* __restrict__ d = ca.dst[a];
    const int n4 = ca.n4[a];
    for (int i = blockIdx.x*256 + threadIdx.x; i < n4; i += gridDim.x*256) {
        float4v v = *(const float4v*)(s + (size_t)i*4);
        st4(d + (size_t)i*4, v);
    }
}

// ---------------------------------------------------------------------------
// Merged complex projections, all-bf16, GLOAD16 staging (z = 0:Q, 1:K, 2:V).
// 128(M) x 64(N) tile, grid (8,32,3)=768. Epilogue: LDS transpose ->
// coalesced 16B stores. z<2: Y[bh][n][d]; z==2: Y[bh][d][n].
// ---------------------------------------------------------------------------
struct ProjArgs {
    const short* Xr[3]; const short* Xi[3];
    const short* Wr[3]; const short* Wi[3];
    short* Yr[3]; short* Yi[3];
};

__global__ __launch_bounds__(256) void cgemm_proj(ProjArgs pa)
{
    __shared__ short sX[2][128][64];   // 32KB
    __shared__ short sW[2][64][64];    // 16KB
    const int z = blockIdx.z;
    const short* __restrict__ X_r = pa.Xr[z];
    const short* __restrict__ X_i = pa.Xi[z];
    const short* __restrict__ W_r = pa.Wr[z];
    const short* __restrict__ W_i = pa.Wi[z];
    short* __restrict__ Y_r = pa.Yr[z];
    short* __restrict__ Y_i = pa.Yi[z];
    const int transposeOut = (z == 2);

    const int tid  = threadIdx.x;
    const int lane = tid & 63, wave = tid >> 6;
    const int quad = lane >> 4, l16 = lane & 15;
    const int sw8  = l16 & 7;
    const int rsub = lane >> 3;
    const int colg = (lane & 7) ^ rsub;
    const int n0 = blockIdx.x * 64, m0 = blockIdx.y * 128;

    const short nk = (short)0x8000;
    const short8 neg = {nk,nk,nk,nk,nk,nk,nk,nk};

    float4v zf = {0.f,0.f,0.f,0.f};
    float4v Yr[2][4], Yi[2][4];
    #pragma unroll
    for (int ms = 0; ms < 2; ms++)
        #pragma unroll
        for (int t = 0; t < 4; t++) { Yr[ms][t] = zf; Yi[ms][t] = zf; }

    for (int kc = 0; kc < RD; kc += 64) {
        __syncthreads();
        if (wave < 2) {                   // X planes: 128 rows
            const short* gp = wave ? X_i : X_r;
            short* lp = wave ? &sX[1][0][0] : &sX[0][0][0];
            #pragma unroll
            for (int j = 0; j < 16; j++) {
                int row = j*8 + rsub;
                GLOAD16(gp + (size_t)(m0 + row)*RD + kc + colg*8, lp + j*512);
            }
        } else {                          // W planes: 64 rows
            const short* gp = (wave == 3) ? W_i : W_r;
            short* lp = (wave == 3) ? &sW[1][0][0] : &sW[0][0][0];
            #pragma unroll
            for (int j = 0; j < 8; j++) {
                int row = j*8 + rsub;
                GLOAD16(gp + (size_t)(n0 + row)*RD + kc + colg*8, lp + j*512);
            }
        }
        __syncthreads();
        short8 fxr[2][2], fxi[2][2], fxin[2][2];
        #pragma unroll
        for (int ms = 0; ms < 2; ms++)
            #pragma unroll
            for (int ds = 0; ds < 2; ds++) {
                int row = wave*32 + ms*16 + l16;
                int u = ((ds*4 + quad) ^ sw8) * 8;
                fxr[ms][ds]  = *(short8*)&sX[0][row][u];
                fxi[ms][ds]  = *(short8*)&sX[1][row][u];
                fxin[ms][ds] = fxi[ms][ds] ^ neg;
            }
        #pragma unroll
        for (int t = 0; t < 4; t++)
            #pragma unroll
            for (int ds = 0; ds < 2; ds++) {
                int u = ((ds*4 + quad) ^ sw8) * 8;
                short8 wr = *(short8*)&sW[0][t*16 + l16][u];
                short8 wi = *(short8*)&sW[1][t*16 + l16][u];
                #pragma unroll
                for (int ms = 0; ms < 2; ms++) {
                    Yr[ms][t] = MFMA16(fxr[ms][ds],  wr, Yr[ms][t]);
                    Yr[ms][t] = MFMA16(fxin[ms][ds], wi, Yr[ms][t]);   // -Xi*Wi
                    Yi[ms][t] = MFMA16(fxr[ms][ds],  wi, Yi[ms][t]);
                    Yi[ms][t] = MFMA16(fxi[ms][ds],  wr, Yi[ms][t]);
                }
            }
    }

    // ---- epilogue: LDS round-trip -> coalesced 16B stores ----
    const int b = m0 >> 10, h = n0 >> 6, nb = m0 & 1023;
    short* sT = &sX[0][0][0];      // <=17.4KB, fits in sX's 32KB
    short* Yp[2] = { Y_r, Y_i };
    #pragma unroll
    for (int p = 0; p < 2; p++) {
        __syncthreads();
        #pragma unroll
        for (int ms = 0; ms < 2; ms++)
            #pragma unroll
            for (int t = 0; t < 4; t++)
                #pragma unroll
                for (int r = 0; r < 4; r++) {
                    float v = p ? Yi[ms][t][r] : Yr[ms][t][r];
                    int rr = wave*32 + ms*16 + quad*4 + r;  // n-local (0..127)
                    int cc = t*16 + l16;                    // d (0..63)
                    if (!transposeOut) sT[rr*68 + cc]  = (short)f2b(v);
                    else               sT[cc*132 + rr] = (short)f2b(v);
                }
        __syncthreads();
        #pragma unroll
        for (int it = 0; it < 4; it++) {
            int idx = it*256 + tid;           // 0..1023 16B-units
            int rr, c8;
            size_t o;
            const short* sp;
            if (!transposeOut) {              // 128 rows x 64 cols
                rr = idx >> 3; c8 = (idx & 7)*8;
                sp = &sT[rr*68 + c8];
                o = (((size_t)(b*NHEAD + h))*NSEQ + nb + rr)*HD + c8;
            } else {                          // 64 rows(d) x 128 cols(n)
                rr = idx >> 4; c8 = (idx & 15)*8;
                sp = &sT[rr*132 + c8];
                o = (((size_t)(b*NHEAD + h))*HD + rr)*NSEQ + nb + c8;
            }
            short4v a = *(short4v*)sp;
            short4v bq = *(short4v*)(sp + 4);
            short8 v8 = { a[0],a[1],a[2],a[3], bq[0],bq[1],bq[2],bq[3] };
            *(short8*)&Yp[p][o] = v8;
        }
    }
}

// ---------------------------------------------------------------------------
// Flash attention with 32x32x16 MFMA (2x MAC per LDS byte vs 16x16x32).
// Block = 4 waves (256 thr) = 2 q-halves x 2 key-halves; each wave computes
// 32 q rows x 32 keys per 64-key round. Q A-frags direct-global (m=lane&31,
// k=(lane>>5)*8+j), loop-invariant. K/V B-frags b128 from XOR-swizzled LDS.
// C/D layout: col=lane&31, row=(reg&3)+8*(reg>>2)+4*(lane>>5) [m74/m101].
// R17 FIX: PV B-fragment unit index includes khalf*4 (R16 dropped it).
// No-max softmax, additive (O,l) partials combined via LDS at end.
// Grid 512 qt-major (XCD = bh%8). LDS 44KB -> 2 blocks/CU (grid-capped).
// ---------------------------------------------------------------------------
__global__ __launch_bounds__(256) void attn_mfma(
    const short* __restrict__ Qp_r, const short* __restrict__ Qp_i,
    const short* __restrict__ Kp_r, const short* __restrict__ Kp_i,
    const short* __restrict__ Vp_r, const short* __restrict__ Vp_i,
    const unsigned char* __restrict__ mask,
    short* __restrict__ Ar, short* __restrict__ Ai)
{
    __shared__ __align__(16) char smem[44032];
    short (*sK)[64][64] = (short(*)[64][64])smem;            // Kr,Ki 16KB
    short (*sV)[64][64] = (short(*)[64][64])(smem + 16384);  // Vr,Vi 16KB
    short (*sP)[32][40] = (short(*)[32][40])(smem + 32768);  // 4 waves, 10KB
    unsigned char* smask = (unsigned char*)(smem + 43008);   // 1KB

    const int tid  = threadIdx.x;
    const int lane = tid & 63, wave = tid >> 6;      // 0..3
    const int l32  = lane & 31;                      // MFMA col / A row
    const int lh   = lane >> 5;                      // k-half within frag
    const int sw7  = lane & 7;                       // XOR swizzle key
    const int qhalf = wave >> 1;                     // 0..1 (32 q rows)
    const int khalf = wave & 1;                      // 0..1 (32 keys)
    const int qt = blockIdx.x >> 5;                  // qt-major
    const int bh = blockIdx.x & 31;                  // XCD = bh % 8
    const int b  = bh >> 3, h = bh & 7;
    const size_t base = (size_t)bh * (NSEQ*HD);

    const int rsub = lane >> 3;
    const int colg = (lane & 7) ^ rsub;

    ((int*)smask)[tid] = ((const int*)(mask + b*NSEQ))[tid];

    // staging: wave -> one plane (0:Kr 1:Ki 2:Vr 3:Vi), 8 chunks of 1KB
    const short* sgp = (wave == 0) ? Kp_r : (wave == 1) ? Kp_i
                     : (wave == 2) ? Vp_r : Vp_i;
    const int sisV = (wave >= 2);
    short* slp = (short*)(smem + wave*8192);

    // ---- Q A-fragments direct from global (once): m=l32, k=c*16+lh*8 ----
    const short nk = (short)0x8000;
    const short8 neg = {nk,nk,nk,nk,nk,nk,nk,nk};
    short8 fqr[4], fqi[4], fqrn[4];
    #pragma unroll
    for (int c = 0; c < 4; c++) {
        size_t qo = base + (size_t)(qt*64 + qhalf*32 + l32)*HD + c*16 + lh*8;
        fqr[c]  = *(const short8*)&Qp_r[qo];
        fqi[c]  = *(const short8*)&Qp_i[qo];
        fqrn[c] = fqr[c] ^ neg;
    }

    float16v Or0 = {0}, Or1 = {0}, Oi0 = {0}, Oi1 = {0};
    float lrow[16];
    #pragma unroll
    for (int r = 0; r < 16; r++) lrow[r] = 0.f;

    const float C2 = 0.18033688f;   // 0.125 * log2(e)

    for (int kt = 0; kt < 16; kt++) {
        const int k0 = kt*64;
        __syncthreads();
        {   // stage this wave's plane: 8 chunks, XOR-swizzled 16B units
            #pragma unroll
            for (int j = 0; j < 8; j++) {
                int row = j*8 + rsub;
                const short* g = sisV
                    ? sgp + base + (size_t)row*NSEQ + k0 + colg*8
                    : sgp + base + (size_t)(k0 + row)*HD + colg*8;
                GLOAD16(g, slp + j*512);
            }
        }
        __syncthreads();

        // ---- S = Q conj(K)^T : one 32x32 tile, K-dim 64 (4 chunks) ----
        float16v Sr = {0}, Si = {0};
        const int krow = khalf*32 + l32;
        #pragma unroll
        for (int c = 0; c < 4; c++) {
            int u = ((c*2 + lh) ^ sw7) * 8;       // d-units span 0..7
            short8 kr = *(short8*)&sK[0][krow][u];
            short8 ki = *(short8*)&sK[1][krow][u];
            Sr = MFMA32(fqr[c],  kr, Sr);
            Sr = MFMA32(fqi[c],  ki, Sr);     // +QiKi (conj)
            Si = MFMA32(fqi[c],  kr, Si);
            Si = MFMA32(fqrn[c], ki, Si);     // -QrKi
        }

        // ---- e = exp(|S|/8) (no max shift); mask uniform per lane ----
        bool mv = smask[k0 + khalf*32 + l32] != 0;
        #pragma unroll
        for (int r = 0; r < 16; r++) {
            float a = Sr[r], c = Si[r];
            float x = fmaf(a, a, c*c);
            float s = __builtin_amdgcn_sqrtf(x);
            float e = mv ? __builtin_amdgcn_exp2f(C2 * s) : 0.f;
            lrow[r] += e;
            int row = (r & 3) + 8*(r >> 2) + 4*lh;     // C-layout q row
            sP[wave][row][l32] = (short)f2b(e);
        }

        // ---- O += P @ V : 2 d-tiles x 2 key-chunks ----
        #pragma unroll
        for (int c = 0; c < 2; c++) {
            short8 fp = *(short8*)&sP[wave][l32][c*16 + lh*8];
            #pragma unroll
            for (int dt = 0; dt < 2; dt++) {
                int vrow = dt*32 + l32;
                // key units within 64-key tile: khalf*4 + c*2 + lh  [R17 FIX]
                int u = ((khalf*4 + c*2 + lh) ^ sw7) * 8;
                short8 vr = *(short8*)&sV[0][vrow][u];
                short8 vi = *(short8*)&sV[1][vrow][u];
                if (dt == 0) { Or0 = MFMA32(fp, vr, Or0); Oi0 = MFMA32(fp, vi, Oi0); }
                else         { Or1 = MFMA32(fp, vr, Or1); Oi1 = MFMA32(fp, vi, Oi1); }
            }
        }
    }

    // ---- combine key-half partners (khalf 1 -> 0) through reused LDS ----
    __syncthreads();                          // all sK/sV/sP reads done
    float* sC = (float*)smem;                 // 32KB O partials
    float* sL = (float*)(smem + 32768);       // 8KB  l partials
    if (khalf == 1) {
        #pragma unroll
        for (int r = 0; r < 16; r++) {
            int o0 = (qhalf*2048 + r*64 + lane)*2;
            sC[o0]          = Or0[r];
            sC[o0 + 1]      = Oi0[r];
            int o1 = (qhalf*2048 + 1024 + r*64 + lane)*2;
            sC[o1]          = Or1[r];
            sC[o1 + 1]      = Oi1[r];
            sL[(qhalf*16 + r)*64 + lane] = lrow[r];
        }
    }
    __syncthreads();
    if (khalf == 0) {
        float inv[16];
        #pragma unroll
        for (int r = 0; r < 16; r++) {
            int o0 = (qhalf*2048 + r*64 + lane)*2;
            Or0[r] += sC[o0];     Oi0[r] += sC[o0 + 1];
            int o1 = (qhalf*2048 + 1024 + r*64 + lane)*2;
            Or1[r] += sC[o1];     Oi1[r] += sC[o1 + 1];
            float ls = lrow[r] + sL[(qhalf*16 + r)*64 + lane];
            ls += __shfl_xor(ls, 1,  64);
            ls += __shfl_xor(ls, 2,  64);
            ls += __shfl_xor(ls, 4,  64);
            ls += __shfl_xor(ls, 8,  64);
            ls += __shfl_xor(ls, 16, 64);     // stays within 32-lane half
            inv[r] = (ls > 0.f) ? 1.f/ls : 0.f;
        }
        #pragma unroll
        for (int r = 0; r < 16; r++) {
            int q = qt*64 + qhalf*32 + (r & 3) + 8*(r >> 2) + 4*lh;
            size_t o = ((size_t)(b*NSEQ + q))*NHD + h*HD;
            Ar[o + l32]      = (short)f2b(Or0[r] * inv[r]);
            Ai[o + l32]      = (short)f2b(Oi0[r] * inv[r]);
            Ar[o + 32 + l32] = (short)f2b(Or1[r] * inv[r]);
            Ai[o + 32 + l32] = (short)f2b(Oi1[r] * inv[r]);
        }
    }
}

// ---------------------------------------------------------------------------
// Output projection, all-bf16, GLOAD16 staging, split-N (64x32 tiles).
// Out = A @ (WOr + i WOi)^T; grid (8,64) = 512 blocks, direct fp32 stores.
// ---------------------------------------------------------------------------
__global__ __launch_bounds__(256) void cgemm_out(
    const short* __restrict__ A_r, const short* __restrict__ A_i,
    const short* __restrict__ W_r, const short* __restrict__ W_i,
    float* __restrict__ Out, int writeImagPlane)
{
    __shared__ short sA[2][64][64];
    __shared__ short sW[2][32][64];
    const int tid  = threadIdx.x;
    const int lane = tid & 63, wave = tid >> 6;
    const int quad = lane >> 4, l16 = lane & 15;
    const int sw8  = l16 & 7;
    const int rsub = lane >> 3;
    const int colg = (lane & 7) ^ rsub;
    const int n0 = blockIdx.x * 32, m0 = blockIdx.y * 64;

    const short nk = (short)0x8000;
    const short8 neg = {nk,nk,nk,nk,nk,nk,nk,nk};

    float4v zf = {0.f,0.f,0.f,0.f};
    float4v Yr[2], Yi[2];
    #pragma unroll
    for (int t = 0; t < 2; t++) { Yr[t] = zf; Yi[t] = zf; }

    for (int kc = 0; kc < NHD; kc += 64) {
        __syncthreads();
        {
            if (wave < 2) {
                const short* gp = wave ? A_i : A_r;
                short* lp = wave ? &sA[1][0][0] : &sA[0][0][0];
                #pragma unroll
                for (int j = 0; j < 8; j++) {
                    int row = j*8 + rsub;
                    GLOAD16(gp + (size_t)(m0 + row)*NHD + kc + colg*8, lp + j*512);
                }
            } else {
                const short* gp = (wave == 3) ? W_i : W_r;
                short* lp = (wave == 3) ? &sW[1][0][0] : &sW[0][0][0];
                #pragma unroll
                for (int j = 0; j < 4; j++) {
                    int row = j*8 + rsub;
                    GLOAD16(gp + (size_t)(n0 + row)*NHD + kc + colg*8, lp + j*512);
                }
            }
        }
        __syncthreads();
        short8 far[2], fai[2], fain[2];
        #pragma unroll
        for (int ds = 0; ds < 2; ds++) {
            int u = ((ds*4 + quad) ^ sw8) * 8;
            far[ds]  = *(short8*)&sA[0][wave*16 + l16][u];
            fai[ds]  = *(short8*)&sA[1][wave*16 + l16][u];
            fain[ds] = fai[ds] ^ neg;
        }
        #pragma unroll
        for (int t = 0; t < 2; t++)
            #pragma unroll
            for (int ds = 0; ds < 2; ds++) {
                int u = ((ds*4 + quad) ^ sw8) * 8;
                short8 wr = *(short8*)&sW[0][t*16 + l16][u];
                short8 wi = *(short8*)&sW[1][t*16 + l16][u];
                Yr[t] = MFMA16(far[ds],  wr, Yr[t]);
                Yr[t] = MFMA16(fain[ds], wi, Yr[t]);
                Yi[t] = MFMA16(far[ds],  wi, Yi[t]);
                Yi[t] = MFMA16(fai[ds],  wr, Yi[t]);
            }
    }
    const size_t TOT = (size_t)NBATCH * NSEQ * RD;   // 1,048,576
    #pragma unroll
    for (int t = 0; t < 2; t++)
        #pragma unroll
        for (int r = 0; r < 4; r++) {
            int row = m0 + wave*16 + quad*4 + r;
            int col = n0 + t*16 + l16;
            size_t o = (size_t)row*RD + col;
            Out[o] = Yr[t][r];
            if (writeImagPlane) Out[o + TOT] = Yi[t][r];
        }
}

// ---------------------------------------------------------------------------
extern "C" void kernel_launch(void* const* d_in, const int* in_sizes, int n_in,
                              void* d_out, int out_size, void* d_ws, size_t ws_size,
                              hipStream_t stream)
{
    float* out = (float*)d_out;

    const size_t P = (size_t)NBATCH * NHEAD * NSEQ * HD;   // 2,097,152
    const size_t H = (size_t)NBATCH * NSEQ * RD;           // 1,048,576
    const size_t WSZ = (size_t)NHD * RD;                   // 131,072

    short* bws = (short*)d_ws;
    // bf16 projected planes [0, 24MB)
    short* Qpr = bws + 0*P;  short* Qpi = bws + 1*P;
    short* Kpr = bws + 2*P;  short* Kpi = bws + 3*P;
    short* Vpr = bws + 4*P;  short* Vpi = bws + 5*P;
    // converted-input region @ 24MB (dead after cgemm_proj, except WO)
    short* conv = bws + 6*P;
    short* cX[6]; for (int i = 0; i < 6; i++) cX[i] = conv + i*H;       // 12MB
    short* cW[6]; for (int i = 0; i < 6; i++) cW[i] = conv + 6*H + i*WSZ;
    short* cWOr = conv + 6*H + 6*WSZ;
    short* cWOi = conv + 6*H + 7*WSZ;
    // A planes alias the (dead) converted X region
    short* Apr = conv;          // 4MB
    short* Api = conv + P;      // 4MB
    unsigned char* nmask = (unsigned char*)(conv + 6*H + 8*WSZ);  // 4KB

    const size_t TOT = (size_t)NBATCH * NSEQ * RD;
    const int writeImagPlane = ((size_t)out_size >= 2*TOT) ? 1 : 0;

    ConvArgs ca;
    for (int i = 0; i < 6; i++) {
        ca.src[i] = (const float*)d_in[i];  ca.dst[i] = cX[i];  ca.n4[i] = (int)(H/4);
    }
    for (int i = 0; i < 6; i++) {
        ca.src[6+i] = (const float*)d_in[6+i]; ca.dst[6+i] = cW[i]; ca.n4[6+i] = (int)(WSZ/4);
    }
    ca.src[12] = (const float*)d_in[12]; ca.dst[12] = cWOr; ca.n4[12] = (int)(WSZ/4);
    ca.src[13] = (const float*)d_in[13]; ca.dst[13] = cWOi; ca.n4[13] = (int)(WSZ/4);
    ca.src[14] = (const float*)d_in[14]; ca.dst[14] = (short*)nmask; ca.n4[14] = 0;

    ProjArgs pa;
    pa.Xr[0] = cX[0]; pa.Xi[0] = cX[1];
    pa.Xr[1] = cX[2]; pa.Xi[1] = cX[3];
    pa.Xr[2] = cX[4]; pa.Xi[2] = cX[5];
    pa.Wr[0] = cW[0]; pa.Wi[0] = cW[1];
    pa.Wr[1] = cW[2]; pa.Wi[1] = cW[3];
    pa.Wr[2] = cW[4]; pa.Wi[2] = cW[5];
    pa.Yr[0] = Qpr; pa.Yi[0] = Qpi;
    pa.Yr[1] = Kpr; pa.Yi[1] = Kpi;
    pa.Yr[2] = Vpr; pa.Yi[2] = Vpi;

    convert_bf16<<<dim3(256, 15), 256, 0, stream>>>(ca);
    cgemm_proj<<<dim3(8, 32, 3), 256, 0, stream>>>(pa);
    attn_mfma<<<dim3(512), 256, 0, stream>>>(Qpr, Qpi, Kpr, Kpi, Vpr, Vpi,
                                             nmask, Apr, Api);
    cgemm_out<<<dim3(8, 64), 256, 0, stream>>>(Apr, Api, cWOr, cWOi, out,
                                               writeImagPlane);
}

// Round 18
// 172.330 us; speedup vs baseline: 1.0260x; 1.0260x over previous
//
#include <hip/hip_runtime.h>
#include <math.h>

#define NBATCH 4
#define NSEQ   1024
#define RD     256
#define NHEAD  8
#define HD     64
#define NHD    512   // NHEAD*HD

typedef __attribute__((ext_vector_type(8))) short  short8;
typedef __attribute__((ext_vector_type(4))) short  short4v;
typedef __attribute__((ext_vector_type(4))) float  float4v;

#define MFMA16(a,b,c) __builtin_amdgcn_mfma_f32_16x16x32_bf16(a,b,c,0,0,0)

typedef const void __attribute__((address_space(1)))* gas_t;
typedef void __attribute__((address_space(3)))* las_t;
#define GLOAD16(g, l) __builtin_amdgcn_global_load_lds((gas_t)(g), (las_t)(l), 16, 0, 0)

static __device__ __forceinline__ unsigned short f2b(float f) {
    union { float f; unsigned u; } x; x.f = f;
    unsigned r = x.u + 0x7fffu + ((x.u >> 16) & 1u);   // RNE; inputs finite
    return (unsigned short)(r >> 16);
}
static __device__ __forceinline__ void st4(short* dst, float4v v) {
    short4v p;
    p[0] = (short)f2b(v[0]); p[1] = (short)f2b(v[1]);
    p[2] = (short)f2b(v[2]); p[3] = (short)f2b(v[3]);
    *(short4v*)dst = p;
}

// ---------------------------------------------------------------------------
// Bulk fp32 -> bf16 conversion of all inputs + mask normalization (y == 14).
// ---------------------------------------------------------------------------
struct ConvArgs { const float* src[15]; short* dst[15]; int n4[15]; };

__global__ __launch_bounds__(256) void convert_bf16(ConvArgs ca)
{
    const int a = blockIdx.y;
    if (a == 14) {                      // mask normalization (validated R4)
        if (blockIdx.x != 0) return;
        __shared__ int isByteLayout;
        const int t = threadIdx.x;      // 256 threads
        if (t == 0) isByteLayout = 0;
        __syncthreads();
        const int* mi = (const int*)ca.src[14];
        #pragma unroll
        for (int j = 0; j < 4; j++) {
            int v = mi[t*4 + j];        // first 4096 bytes under both layouts
            if (v & ~1) isByteLayout = 1;
        }
        __syncthreads();
        unsigned char* nm = (unsigned char*)ca.dst[14];
        const unsigned char* mb = (const unsigned char*)ca.src[14];
        if (isByteLayout) {
            #pragma unroll
            for (int j = 0; j < 16; j++) { int k = t*16 + j; nm[k] = mb[k] ? 1 : 0; }
        } else {
            #pragma unroll
            for (int j = 0; j < 16; j++) { int k = t*16 + j; nm[k] = mi[k] ? 1 : 0; }
        }
        return;
    }
    const float* __restrict__ s = ca.src[a];
    short* __restrict__ d = ca.dst[a];
    const int n4 = ca.n4[a];
    for (int i = blockIdx.x*256 + threadIdx.x; i < n4; i += gridDim.x*256) {
        float4v v = *(const float4v*)(s + (size_t)i*4);
        st4(d + (size_t)i*4, v);
    }
}

// ---------------------------------------------------------------------------
// Merged complex projections, all-bf16, GLOAD16 staging (z = 0:Q, 1:K, 2:V).
// 128(M) x 64(N) tile, grid (8,32,3)=768. Epilogue: LDS transpose ->
// coalesced 16B stores. z<2: Y[bh][n][d]; z==2: Y[bh][d][n].
// ---------------------------------------------------------------------------
struct ProjArgs {
    const short* Xr[3]; const short* Xi[3];
    const short* Wr[3]; const short* Wi[3];
    short* Yr[3]; short* Yi[3];
};

__global__ __launch_bounds__(256) void cgemm_proj(ProjArgs pa)
{
    __shared__ short sX[2][128][64];   // 32KB
    __shared__ short sW[2][64][64];    // 16KB
    const int z = blockIdx.z;
    const short* __restrict__ X_r = pa.Xr[z];
    const short* __restrict__ X_i = pa.Xi[z];
    const short* __restrict__ W_r = pa.Wr[z];
    const short* __restrict__ W_i = pa.Wi[z];
    short* __restrict__ Y_r = pa.Yr[z];
    short* __restrict__ Y_i = pa.Yi[z];
    const int transposeOut = (z == 2);

    const int tid  = threadIdx.x;
    const int lane = tid & 63, wave = tid >> 6;
    const int quad = lane >> 4, l16 = lane & 15;
    const int sw8  = l16 & 7;
    const int rsub = lane >> 3;
    const int colg = (lane & 7) ^ rsub;
    const int n0 = blockIdx.x * 64, m0 = blockIdx.y * 128;

    const short nk = (short)0x8000;
    const short8 neg = {nk,nk,nk,nk,nk,nk,nk,nk};

    float4v zf = {0.f,0.f,0.f,0.f};
    float4v Yr[2][4], Yi[2][4];
    #pragma unroll
    for (int ms = 0; ms < 2; ms++)
        #pragma unroll
        for (int t = 0; t < 4; t++) { Yr[ms][t] = zf; Yi[ms][t] = zf; }

    for (int kc = 0; kc < RD; kc += 64) {
        __syncthreads();
        if (wave < 2) {                   // X planes: 128 rows
            const short* gp = wave ? X_i : X_r;
            short* lp = wave ? &sX[1][0][0] : &sX[0][0][0];
            #pragma unroll
            for (int j = 0; j < 16; j++) {
                int row = j*8 + rsub;
                GLOAD16(gp + (size_t)(m0 + row)*RD + kc + colg*8, lp + j*512);
            }
        } else {                          // W planes: 64 rows
            const short* gp = (wave == 3) ? W_i : W_r;
            short* lp = (wave == 3) ? &sW[1][0][0] : &sW[0][0][0];
            #pragma unroll
            for (int j = 0; j < 8; j++) {
                int row = j*8 + rsub;
                GLOAD16(gp + (size_t)(n0 + row)*RD + kc + colg*8, lp + j*512);
            }
        }
        __syncthreads();
        short8 fxr[2][2], fxi[2][2], fxin[2][2];
        #pragma unroll
        for (int ms = 0; ms < 2; ms++)
            #pragma unroll
            for (int ds = 0; ds < 2; ds++) {
                int row = wave*32 + ms*16 + l16;
                int u = ((ds*4 + quad) ^ sw8) * 8;
                fxr[ms][ds]  = *(short8*)&sX[0][row][u];
                fxi[ms][ds]  = *(short8*)&sX[1][row][u];
                fxin[ms][ds] = fxi[ms][ds] ^ neg;
            }
        #pragma unroll
        for (int t = 0; t < 4; t++)
            #pragma unroll
            for (int ds = 0; ds < 2; ds++) {
                int u = ((ds*4 + quad) ^ sw8) * 8;
                short8 wr = *(short8*)&sW[0][t*16 + l16][u];
                short8 wi = *(short8*)&sW[1][t*16 + l16][u];
                #pragma unroll
                for (int ms = 0; ms < 2; ms++) {
                    Yr[ms][t] = MFMA16(fxr[ms][ds],  wr, Yr[ms][t]);
                    Yr[ms][t] = MFMA16(fxin[ms][ds], wi, Yr[ms][t]);   // -Xi*Wi
                    Yi[ms][t] = MFMA16(fxr[ms][ds],  wi, Yi[ms][t]);
                    Yi[ms][t] = MFMA16(fxi[ms][ds],  wr, Yi[ms][t]);
                }
            }
    }

    // ---- epilogue: LDS round-trip -> coalesced 16B stores ----
    const int b = m0 >> 10, h = n0 >> 6, nb = m0 & 1023;
    short* sT = &sX[0][0][0];      // <=17.4KB, fits in sX's 32KB
    short* Yp[2] = { Y_r, Y_i };
    #pragma unroll
    for (int p = 0; p < 2; p++) {
        __syncthreads();
        #pragma unroll
        for (int ms = 0; ms < 2; ms++)
            #pragma unroll
            for (int t = 0; t < 4; t++)
                #pragma unroll
                for (int r = 0; r < 4; r++) {
                    float v = p ? Yi[ms][t][r] : Yr[ms][t][r];
                    int rr = wave*32 + ms*16 + quad*4 + r;  // n-local (0..127)
                    int cc = t*16 + l16;                    // d (0..63)
                    if (!transposeOut) sT[rr*68 + cc]  = (short)f2b(v);
                    else               sT[cc*132 + rr] = (short)f2b(v);
                }
        __syncthreads();
        #pragma unroll
        for (int it = 0; it < 4; it++) {
            int idx = it*256 + tid;           // 0..1023 16B-units
            int rr, c8;
            size_t o;
            const short* sp;
            if (!transposeOut) {              // 128 rows x 64 cols
                rr = idx >> 3; c8 = (idx & 7)*8;
                sp = &sT[rr*68 + c8];
                o = (((size_t)(b*NHEAD + h))*NSEQ + nb + rr)*HD + c8;
            } else {                          // 64 rows(d) x 128 cols(n)
                rr = idx >> 4; c8 = (idx & 15)*8;
                sp = &sT[rr*132 + c8];
                o = (((size_t)(b*NHEAD + h))*HD + rr)*NSEQ + nb + c8;
            }
            short4v a = *(short4v*)sp;
            short4v bq = *(short4v*)(sp + 4);
            short8 v8 = { a[0],a[1],a[2],a[3], bq[0],bq[1],bq[2],bq[3] };
            *(short8*)&Yp[p][o] = v8;
        }
    }
}

// ---------------------------------------------------------------------------
// Flash attention: DOUBLE-BUFFERED single-barrier K-loop (best measured:
// R14, 173.9us total). Per round: barrier -> issue async GLOAD16 of tile
// kt+1 into buf B -> compute tile kt from buf A. Block = 8 waves (512 thr)
// = 4 q-strips x 2 key-halves, 64 q rows; grid 512 qt-major (XCD = bh%8).
// Q frags direct-global once. No-max softmax; additive (O,l) partials
// combined at end via LDS. LDS 75KB -> 2 blocks/CU (grid-capped).
// ---------------------------------------------------------------------------
__global__ __launch_bounds__(512) void attn_mfma(
    const short* __restrict__ Qp_r, const short* __restrict__ Qp_i,
    const short* __restrict__ Kp_r, const short* __restrict__ Kp_i,
    const short* __restrict__ Vp_r, const short* __restrict__ Vp_i,
    const unsigned char* __restrict__ mask,
    short* __restrict__ Ar, short* __restrict__ Ai)
{
    __shared__ __align__(16) char smem[76800];
    // buf b at smem + b*32768: Kr +0, Ki +8192, Vr +16384, Vi +24576
    short (*sP)[16][40] = (short(*)[16][40])(smem + 65536);  // 8 waves, 10KB
    unsigned char* smask = (unsigned char*)(smem + 75776);   // 1KB

    const int tid  = threadIdx.x;
    const int lane = tid & 63, wave = tid >> 6;      // 0..7
    const int quad = lane >> 4, l16 = lane & 15;
    const int sw8  = l16 & 7;
    const int qstrip = wave >> 1;                    // 0..3
    const int khalf  = wave & 1;                     // 0..1
    const int qt = blockIdx.x >> 5;                  // qt-major
    const int bh = blockIdx.x & 31;                  // XCD = bh % 8
    const int b  = bh >> 3, h = bh & 7;
    const size_t base = (size_t)bh * (NSEQ*HD);

    const int rsub = lane >> 3;
    const int colg = (lane & 7) ^ rsub;

    if (tid < 256) ((int*)smask)[tid] = ((const int*)(mask + b*NSEQ))[tid];

    // this wave's staging plane (0:Kr 1:Ki 2:Vr 3:Vi), 4 chunks of 1KB
    const int splane = wave >> 1;
    const short* sgp = (splane == 0) ? Kp_r : (splane == 1) ? Kp_i
                     : (splane == 2) ? Vp_r : Vp_i;
    const int sisV = (splane >= 2);
    const int soff = splane * 8192;

    // ---- Q fragments direct from global (once, out of loop) ----
    const short nk = (short)0x8000;
    const short8 neg = {nk,nk,nk,nk,nk,nk,nk,nk};
    short8 fqr[2], fqi[2], fqrn[2];
    #pragma unroll
    for (int ds = 0; ds < 2; ds++) {
        size_t qo = base + (size_t)(qt*64 + qstrip*16 + l16)*HD + ds*32 + quad*8;
        fqr[ds]  = *(const short8*)&Qp_r[qo];
        fqi[ds]  = *(const short8*)&Qp_i[qo];
        fqrn[ds] = fqr[ds] ^ neg;
    }

    float4v zf = {0.f,0.f,0.f,0.f};
    float4v Or[4], Oi[4];
    float lrow[4];
    #pragma unroll
    for (int t = 0; t < 4; t++) { Or[t] = zf; Oi[t] = zf; }
    #pragma unroll
    for (int r = 0; r < 4; r++) lrow[r] = 0.f;

    const float C2 = 0.18033688f;   // 0.125 * log2(e)

    // ---- prologue: stage tile 0 into buf 0 ----
    {
        short* lp = (short*)(smem + soff);
        #pragma unroll
        for (int jj = 0; jj < 4; jj++) {
            int j = (wave & 1)*4 + jj;
            int row = j*8 + rsub;
            const short* g = sisV
                ? sgp + base + (size_t)row*NSEQ + colg*8
                : sgp + base + (size_t)row*HD + colg*8;
            GLOAD16(g, lp + j*512);
        }
    }

    for (int kt = 0; kt < 16; kt++) {
        __syncthreads();    // buf[kt&1] staged (vmcnt drained); prev reads done

        // ---- issue async staging of tile kt+1 into the other buffer ----
        if (kt + 1 < 16) {
            const int kn = (kt + 1) * 64;
            short* lp = (short*)(smem + ((kt + 1) & 1)*32768 + soff);
            #pragma unroll
            for (int jj = 0; jj < 4; jj++) {
                int j = (wave & 1)*4 + jj;
                int row = j*8 + rsub;
                const short* g = sisV
                    ? sgp + base + (size_t)row*NSEQ + kn + colg*8
                    : sgp + base + (size_t)(kn + row)*HD + colg*8;
                GLOAD16(g, lp + j*512);
            }
        }

        // ---- compute from buf[kt&1] ----
        const char* buf = smem + (kt & 1)*32768;
        short (*sK0)[64] = (short(*)[64])(buf);
        short (*sK1)[64] = (short(*)[64])(buf + 8192);
        short (*sV0)[64] = (short(*)[64])(buf + 16384);
        short (*sV1)[64] = (short(*)[64])(buf + 24576);
        const int k0 = kt*64;

        // S = Q conj(K)^T over this wave's 32-key half
        float4v Sr[2], Si[2];
        Sr[0] = zf; Sr[1] = zf; Si[0] = zf; Si[1] = zf;
        #pragma unroll
        for (int t = 0; t < 2; t++)
            #pragma unroll
            for (int ds = 0; ds < 2; ds++) {
                int u = ((ds*4 + quad) ^ sw8) * 8;
                int krow = khalf*32 + t*16 + l16;
                short8 kr = *(short8*)&sK0[krow][u];
                short8 ki = *(short8*)&sK1[krow][u];
                Sr[t] = MFMA16(fqr[ds],  kr, Sr[t]);
                Sr[t] = MFMA16(fqi[ds],  ki, Sr[t]);
                Si[t] = MFMA16(fqi[ds],  kr, Si[t]);
                Si[t] = MFMA16(fqrn[ds], ki, Si[t]);
            }

        // e = exp(|S|/8) (no max shift), per-lane l, P strip
        #pragma unroll
        for (int t = 0; t < 2; t++) {
            bool mv = smask[k0 + khalf*32 + t*16 + l16] != 0;
            #pragma unroll
            for (int r = 0; r < 4; r++) {
                float a = Sr[t][r], c = Si[t][r];
                float x = fmaf(a, a, c*c);
                float s = __builtin_amdgcn_sqrtf(x);
                float e = mv ? __builtin_amdgcn_exp2f(C2 * s) : 0.f;
                lrow[r] += e;
                sP[wave][quad*4 + r][t*16 + l16] = (short)f2b(e);
            }
        }

        // O += P @ V over this wave's 32 keys (K=32, one frag)
        {
            short8 fp = *(short8*)&sP[wave][l16][quad*8];
            #pragma unroll
            for (int t = 0; t < 4; t++) {
                int u = ((khalf*4 + quad) ^ sw8) * 8;
                short8 vr = *(short8*)&sV0[t*16 + l16][u];
                short8 vi = *(short8*)&sV1[t*16 + l16][u];
                Or[t] = MFMA16(fp, vr, Or[t]);
                Oi[t] = MFMA16(fp, vi, Oi[t]);
            }
        }
    }

    // ---- combine key-half partners (khalf 1 -> 0) through reused LDS ----
    __syncthreads();                          // all buf/sP reads done
    float* sC = (float*)smem;                 // 32KB O partials
    float* sL = (float*)(smem + 32768);       // 4KB  l partials
    if (khalf == 1) {
        #pragma unroll
        for (int t = 0; t < 4; t++)
            #pragma unroll
            for (int r = 0; r < 4; r++) {
                int o8 = ((qstrip*4 + t)*64 + lane)*8 + r*2;
                sC[o8]     = Or[t][r];
                sC[o8 + 1] = Oi[t][r];
            }
        int lo = (qstrip*64 + lane)*4;
        #pragma unroll
        for (int r = 0; r < 4; r++) sL[lo + r] = lrow[r];
    }
    __syncthreads();
    if (khalf == 0) {
        #pragma unroll
        for (int t = 0; t < 4; t++)
            #pragma unroll
            for (int r = 0; r < 4; r++) {
                int o8 = ((qstrip*4 + t)*64 + lane)*8 + r*2;
                Or[t][r] += sC[o8];
                Oi[t][r] += sC[o8 + 1];
            }
        int lo = (qstrip*64 + lane)*4;
        float inv[4];
        #pragma unroll
        for (int r = 0; r < 4; r++) {
            float ls = lrow[r] + sL[lo + r];
            ls += __shfl_xor(ls, 1, 64);
            ls += __shfl_xor(ls, 2, 64);
            ls += __shfl_xor(ls, 4, 64);
            ls += __shfl_xor(ls, 8, 64);
            inv[r] = (ls > 0.f) ? 1.f/ls : 0.f;
        }
        #pragma unroll
        for (int t = 0; t < 4; t++)
            #pragma unroll
            for (int r = 0; r < 4; r++) {
                int q = qt*64 + qstrip*16 + quad*4 + r;
                int d = t*16 + l16;
                size_t o = ((size_t)(b*NSEQ + q))*NHD + h*HD + d;
                Ar[o] = (short)f2b(Or[t][r] * inv[r]);
                Ai[o] = (short)f2b(Oi[t][r] * inv[r]);
            }
    }
}

// ---------------------------------------------------------------------------
// Output projection, all-bf16, GLOAD16 staging, split-N (64x32 tiles).
// Out = A @ (WOr + i WOi)^T; grid (8,64) = 512 blocks, direct fp32 stores.
// ---------------------------------------------------------------------------
__global__ __launch_bounds__(256) void cgemm_out(
    const short* __restrict__ A_r, const short* __restrict__ A_i,
    const short* __restrict__ W_r, const short* __restrict__ W_i,
    float* __restrict__ Out, int writeImagPlane)
{
    __shared__ short sA[2][64][64];
    __shared__ short sW[2][32][64];
    const int tid  = threadIdx.x;
    const int lane = tid & 63, wave = tid >> 6;
    const int quad = lane >> 4, l16 = lane & 15;
    const int sw8  = l16 & 7;
    const int rsub = lane >> 3;
    const int colg = (lane & 7) ^ rsub;
    const int n0 = blockIdx.x * 32, m0 = blockIdx.y * 64;

    const short nk = (short)0x8000;
    const short8 neg = {nk,nk,nk,nk,nk,nk,nk,nk};

    float4v zf = {0.f,0.f,0.f,0.f};
    float4v Yr[2], Yi[2];
    #pragma unroll
    for (int t = 0; t < 2; t++) { Yr[t] = zf; Yi[t] = zf; }

    for (int kc = 0; kc < NHD; kc += 64) {
        __syncthreads();
        {
            if (wave < 2) {
                const short* gp = wave ? A_i : A_r;
                short* lp = wave ? &sA[1][0][0] : &sA[0][0][0];
                #pragma unroll
                for (int j = 0; j < 8; j++) {
                    int row = j*8 + rsub;
                    GLOAD16(gp + (size_t)(m0 + row)*NHD + kc + colg*8, lp + j*512);
                }
            } else {
                const short* gp = (wave == 3) ? W_i : W_r;
                short* lp = (wave == 3) ? &sW[1][0][0] : &sW[0][0][0];
                #pragma unroll
                for (int j = 0; j < 4; j++) {
                    int row = j*8 + rsub;
                    GLOAD16(gp + (size_t)(n0 + row)*NHD + kc + colg*8, lp + j*512);
                }
            }
        }
        __syncthreads();
        short8 far[2], fai[2], fain[2];
        #pragma unroll
        for (int ds = 0; ds < 2; ds++) {
            int u = ((ds*4 + quad) ^ sw8) * 8;
            far[ds]  = *(short8*)&sA[0][wave*16 + l16][u];
            fai[ds]  = *(short8*)&sA[1][wave*16 + l16][u];
            fain[ds] = fai[ds] ^ neg;
        }
        #pragma unroll
        for (int t = 0; t < 2; t++)
            #pragma unroll
            for (int ds = 0; ds < 2; ds++) {
                int u = ((ds*4 + quad) ^ sw8) * 8;
                short8 wr = *(short8*)&sW[0][t*16 + l16][u];
                short8 wi = *(short8*)&sW[1][t*16 + l16][u];
                Yr[t] = MFMA16(far[ds],  wr, Yr[t]);
                Yr[t] = MFMA16(fain[ds], wi, Yr[t]);
                Yi[t] = MFMA16(far[ds],  wi, Yi[t]);
                Yi[t] = MFMA16(fai[ds],  wr, Yi[t]);
            }
    }
    const size_t TOT = (size_t)NBATCH * NSEQ * RD;   // 1,048,576
    #pragma unroll
    for (int t = 0; t < 2; t++)
        #pragma unroll
        for (int r = 0; r < 4; r++) {
            int row = m0 + wave*16 + quad*4 + r;
            int col = n0 + t*16 + l16;
            size_t o = (size_t)row*RD + col;
            Out[o] = Yr[t][r];
            if (writeImagPlane) Out[o + TOT] = Yi[t][r];
        }
}

// ---------------------------------------------------------------------------
extern "C" void kernel_launch(void* const* d_in, const int* in_sizes, int n_in,
                              void* d_out, int out_size, void* d_ws, size_t ws_size,
                              hipStream_t stream)
{
    float* out = (float*)d_out;

    const size_t P = (size_t)NBATCH * NHEAD * NSEQ * HD;   // 2,097,152
    const size_t H = (size_t)NBATCH * NSEQ * RD;           // 1,048,576
    const size_t WSZ = (size_t)NHD * RD;                   // 131,072

    short* bws = (short*)d_ws;
    // bf16 projected planes [0, 24MB)
    short* Qpr = bws + 0*P;  short* Qpi = bws + 1*P;
    short* Kpr = bws + 2*P;  short* Kpi = bws + 3*P;
    short* Vpr = bws + 4*P;  short* Vpi = bws + 5*P;
    // converted-input region @ 24MB (dead after cgemm_proj, except WO)
    short* conv = bws + 6*P;
    short* cX[6]; for (int i = 0; i < 6; i++) cX[i] = conv + i*H;       // 12MB
    short* cW[6]; for (int i = 0; i < 6; i++) cW[i] = conv + 6*H + i*WSZ;
    short* cWOr = conv + 6*H + 6*WSZ;
    short* cWOi = conv + 6*H + 7*WSZ;
    // A planes alias the (dead) converted X region
    short* Apr = conv;          // 4MB
    short* Api = conv + P;      // 4MB
    unsigned char* nmask = (unsigned char*)(conv + 6*H + 8*WSZ);  // 4KB

    const size_t TOT = (size_t)NBATCH * NSEQ * RD;
    const int writeImagPlane = ((size_t)out_size >= 2*TOT) ? 1 : 0;

    ConvArgs ca;
    for (int i = 0; i < 6; i++) {
        ca.src[i] = (const float*)d_in[i];  ca.dst[i] = cX[i];  ca.n4[i] = (int)(H/4);
    }
    for (int i = 0; i < 6; i++) {
        ca.src[6+i] = (const float*)d_in[6+i]; ca.dst[6+i] = cW[i]; ca.n4[6+i] = (int)(WSZ/4);
    }
    ca.src[12] = (const float*)d_in[12]; ca.dst[12] = cWOr; ca.n4[12] = (int)(WSZ/4);
    ca.src[13] = (const float*)d_in[13]; ca.dst[13] = cWOi; ca.n4[13] = (int)(WSZ/4);
    ca.src[14] = (const float*)d_in[14]; ca.dst[14] = (short*)nmask; ca.n4[14] = 0;

    ProjArgs pa;
    pa.Xr[0] = cX[0]; pa.Xi[0] = cX[1];
    pa.Xr[1] = cX[2]; pa.Xi[1] = cX[3];
    pa.Xr[2] = cX[4]; pa.Xi[2] = cX[5];
    pa.Wr[0] = cW[0]; pa.Wi[0] = cW[1];
    pa.Wr[1] = cW[2]; pa.Wi[1] = cW[3];
    pa.Wr[2] = cW[4]; pa.Wi[2] = cW[5];
    pa.Yr[0] = Qpr; pa.Yi[0] = Qpi;
    pa.Yr[1] = Kpr; pa.Yi[1] = Kpi;
    pa.Yr[2] = Vpr; pa.Yi[2] = Vpi;

    convert_bf16<<<dim3(256, 15), 256, 0, stream>>>(ca);
    cgemm_proj<<<dim3(8, 32, 3), 256, 0, stream>>>(pa);
    attn_mfma<<<dim3(512), 512, 0, stream>>>(Qpr, Qpi, Kpr, Kpi, Vpr, Vpi,
                                             nmask, Apr, Api);
    cgemm_out<<<dim3(8, 64), 256, 0, stream>>>(Apr, Api, cWOr, cWOi, out,
                                               writeImagPlane);
}